// Round 12
// baseline (320.393 us; speedup 1.0000x reference)
//
#include <hip/hip_runtime.h>

// VectorQuantizer forward, MI355X. R25 = R23-exact (best, 283.7us) with the
// 282 gram-strip/reduce blocks MOVED from the gemm kernel into combine:
// gemm kernel is now pure GEMM (4096 blocks, sheds ~6.5% slot contention);
// combine runs 282 gram + 256 token blocks (gram rides idle CUs -- combine
// was 1 block/CU). Finalize gate extended: all 538 blocks increment
// done_ctr; the last block (gram or token) runs finalize (threadfence
// release/acquire unchanged). Gram xs reuses combine's q_lds (16B-aligned).
// R24's select-argmin + DCUT 0.10 reverted (+5us). Math: single-product
// bf16 KE=256, exact argmin via fp32 rescore (RTHR), entropy from DCUT-
// window candidates, d^2-norms closed-form. 3 kernels. T=4096, NE=16384.

#define T_TOK 4096
#define NE    16384
#define KD    256
#define KE    256          // single-product K
#define CAP   1024         // candidate slots per token
#define DCUT  0.13f        // capture window above best-so-far global min
#define RTHR  0.004f       // exact-rescore window above approx min

#define NCB   512          // code prep blocks (32 rows each)
#define NZB   128          // z prep blocks (32 tokens each)
#define NGRAM 282          // 280 gram strip jobs + 2 reduce blocks (in combine)
#define NGEMM 4096         // gemm blocks (32 x 128)
#define NCOMB 256          // combine token blocks (16 tokens each)

typedef __attribute__((ext_vector_type(8))) short bf16x8;
typedef __attribute__((ext_vector_type(4))) float f32x4;
typedef unsigned long long u64;

__device__ __forceinline__ short f2bf(float f) {
    unsigned u = __float_as_uint(f);
    u = (u + 0x7FFFu + ((u >> 16) & 1u)) >> 16;   // round-to-nearest-even
    return (short)u;
}
__device__ __forceinline__ float bf2f(short s) {
    return __uint_as_float(((unsigned)(unsigned short)s) << 16);
}

__device__ __forceinline__ void async_load16(const void* g, void* l) {
    __builtin_amdgcn_global_load_lds(
        (const __attribute__((address_space(1))) void*)g,
        (__attribute__((address_space(3))) void*)l, 16, 0, 0);
}

// ---------------- megaprep: codes | z | init, branch on blockIdx ---------
__global__ __launch_bounds__(256)
void megaprep_kernel(const float* __restrict__ wk, const float* __restrict__ wg,
                     const float* __restrict__ z,
                     float* __restrict__ enorm, float* __restrict__ e2k,
                     float* __restrict__ e2s, short* __restrict__ Es,
                     float* __restrict__ znorm, float* __restrict__ z2k,
                     float* __restrict__ z2s, short* __restrict__ Zs,
                     float* __restrict__ SVeS, float* __restrict__ SVeV,
                     float* __restrict__ SVzS, float* __restrict__ SVzV,
                     float* __restrict__ mompart,
                     u64* __restrict__ packed, float* __restrict__ avg_num,
                     int* __restrict__ ncand, float* __restrict__ scal,
                     float* __restrict__ G, int* __restrict__ done_ctr) {
    int b = blockIdx.x, tid = threadIdx.x;
    if (b >= NCB + NZB) {                    // ---- init branch ----
        int gid = (b - NCB - NZB) * 256 + tid;
        for (int i = gid; i < 81920; i += 2048) G[i] = 0.f;
        for (int i = gid; i < NE; i += 2048) avg_num[i] = 0.f;
        for (int i = gid; i < T_TOK; i += 2048) { packed[i] = ~0ull; ncand[i] = 0; }
        if (gid < 8) scal[gid] = 0.f;
        if (gid == 8) *done_ctr = 0;
        return;
    }

    __shared__ float xs[32][257];            // 32.9 KB
    __shared__ float ps[32][8];
    __shared__ float rnorm[32][2];
    __shared__ float rw[32][2];

    if (b < NCB) {                           // ---- codes branch ----
        int n0 = b * 32;
#pragma unroll
        for (int i = 0; i < 8; ++i) {
            int idx = tid + i * 256;
            xs[idx >> 6][idx & 63] = wk[(size_t)n0 * 64 + idx];
        }
#pragma unroll
        for (int i = 0; i < 24; ++i) {
            int idx = tid + i * 256;
            xs[idx / 192][64 + idx % 192] = wg[(size_t)n0 * 192 + idx];
        }
        __syncthreads();
        {
            int r = tid & 31, part = tid >> 5;
            float s = 0.f;
            for (int j = 0; j < 32; ++j) { float v = xs[r][part * 32 + j]; s = fmaf(v, v, s); }
            ps[r][part] = s;
        }
        __syncthreads();
        if (tid < 32) {
            float sk = ps[tid][0] + ps[tid][1];
            float sg = ps[tid][2] + ps[tid][3] + ps[tid][4] + ps[tid][5] + ps[tid][6] + ps[tid][7];
            float nk = fmaxf(sqrtf(sk), 1e-12f), ng = fmaxf(sqrtf(sg), 1e-12f);
            float ek2 = sk / (nk * nk), eg2 = sg / (ng * ng);
            rnorm[tid][0] = 1.f / nk; rnorm[tid][1] = 1.f / ng;
            rw[tid][0] = ek2; rw[tid][1] = eg2;
            e2k[n0 + tid] = ek2; e2s[n0 + tid] = ek2 + eg2;
        }
        __syncthreads();
        int c = tid;
        for (int i = 0; i < 32; ++i) {
            float y = xs[i][c] * rnorm[i][(c < 64) ? 0 : 1];
            enorm[(size_t)(n0 + i) * KD + c] = y;
            Es[(size_t)(n0 + i) * KE + c] = f2bf(-2.f * y);
        }
        {
            int sel = (c < 64) ? 0 : 1;
            float S = 0.f, V = 0.f;
            for (int r = 0; r < 32; ++r) {
                float y = xs[r][c] * rnorm[r][sel];
                S += y; V = fmaf(rw[r][sel], y, V);
            }
            SVeS[(size_t)b * 256 + c] = S;
            SVeV[(size_t)b * 256 + c] = V;
        }
        if (tid < 32) {
            float a = rw[tid][0], g = rw[tid][1];
            float s0 = a, s1 = a * a, s2 = g, s3 = g * g;
#pragma unroll
            for (int m = 1; m < 32; m <<= 1) {
                s0 += __shfl_xor(s0, m, 64); s1 += __shfl_xor(s1, m, 64);
                s2 += __shfl_xor(s2, m, 64); s3 += __shfl_xor(s3, m, 64);
            }
            if (tid == 0) {
                mompart[b * 4 + 0] = s0; mompart[b * 4 + 1] = s1;
                mompart[b * 4 + 2] = s2; mompart[b * 4 + 3] = s3;
            }
        }
    } else {                                 // ---- z branch ----
        int jz = b - NCB;
        int t0 = jz * 32;
        int bb = t0 >> 10, hw0 = t0 & 1023;
#pragma unroll
        for (int i = 0; i < 32; ++i) {
            int idx = tid + i * 256;
            int cc = idx >> 5, hwl = idx & 31;
            xs[hwl][cc] = z[(((size_t)bb * 256 + cc) << 10) + hw0 + hwl];
        }
        __syncthreads();
        {
            int r = tid & 31, part = tid >> 5;
            float s = 0.f;
            for (int j = 0; j < 32; ++j) { float v = xs[r][part * 32 + j]; s = fmaf(v, v, s); }
            ps[r][part] = s;
        }
        __syncthreads();
        if (tid < 32) {
            float sk = ps[tid][0] + ps[tid][1];
            float sg = ps[tid][2] + ps[tid][3] + ps[tid][4] + ps[tid][5] + ps[tid][6] + ps[tid][7];
            float nk = fmaxf(sqrtf(sk), 1e-12f), ng = fmaxf(sqrtf(sg), 1e-12f);
            float zk2 = sk / (nk * nk), zg2 = sg / (ng * ng);
            rnorm[tid][0] = 1.f / nk; rnorm[tid][1] = 1.f / ng;
            rw[tid][0] = zk2; rw[tid][1] = zg2;
            z2k[t0 + tid] = zk2; z2s[t0 + tid] = zk2 + zg2;
        }
        __syncthreads();
        int c = tid;
        for (int i = 0; i < 32; ++i) {
            float y = xs[i][c] * rnorm[i][(c < 64) ? 0 : 1];
            znorm[(size_t)(t0 + i) * KD + c] = y;
            Zs[(size_t)(t0 + i) * KE + c] = f2bf(y);
        }
        {
            int sel = (c < 64) ? 0 : 1;
            float S = 0.f, V = 0.f;
            for (int r = 0; r < 32; ++r) {
                float y = xs[r][c] * rnorm[r][sel];
                S += y; V = fmaf(rw[r][sel], y, V);
            }
            SVzS[(size_t)jz * 256 + c] = S;
            SVzV[(size_t)jz * 256 + c] = V;
        }
        if (tid < 32) {
            float a = rw[tid][0], g = rw[tid][1];
            float s0 = a, s1 = a * a, s2 = g, s3 = g * g;
#pragma unroll
            for (int m = 1; m < 32; m <<= 1) {
                s0 += __shfl_xor(s0, m, 64); s1 += __shfl_xor(s1, m, 64);
                s2 += __shfl_xor(s2, m, 64); s3 += __shfl_xor(s3, m, 64);
            }
            if (tid == 0) {
                mompart[b * 4 + 0] = s0; mompart[b * 4 + 1] = s1;
                mompart[b * 4 + 2] = s2; mompart[b * 4 + 3] = s3;
            }
        }
    }
}

// ---------------- gram strip job: 32-col i-strip x full W, register acc --------
template <int W>
__device__ __forceinline__ void gram_strip(const float* __restrict__ X, float* __restrict__ G,
                                           int i0s, int r0, int rows, int c0,
                                           float* xs, int tid) {
    const int JW = W / 32;                    // 6 (W=192) or 2 (W=64)
    int ia = tid >> 5;
    int jb = tid & 31;
    float acc[4][JW];
#pragma unroll
    for (int a = 0; a < 4; ++a)
#pragma unroll
        for (int u = 0; u < JW; ++u) acc[a][u] = 0.f;
    for (int rb = 0; rb < rows; rb += 16) {
        __syncthreads();
        for (int lin = tid; lin < 4 * W; lin += 256) {
            int r = lin / (W / 4), f4 = lin % (W / 4);
            *(float4*)&xs[r * W + f4 * 4] =
                *(const float4*)&X[(size_t)(r0 + rb + r) * KD + c0 + f4 * 4];
        }
        __syncthreads();
#pragma unroll 4
        for (int r = 0; r < 16; ++r) {
            float4 xi = *(const float4*)&xs[r * W + i0s + ia * 4];
            float xj[JW];
#pragma unroll
            for (int u = 0; u < JW; ++u) xj[u] = xs[r * W + jb * JW + u];
#pragma unroll
            for (int a = 0; a < 4; ++a)
#pragma unroll
                for (int u = 0; u < JW; ++u)
                    acc[a][u] = fmaf(xi[a], xj[u], acc[a][u]);
        }
    }
#pragma unroll
    for (int a = 0; a < 4; ++a) {
        int i = i0s + ia * 4 + a;
#pragma unroll
        for (int u = 0; u < JW; ++u)
            atomicAdd(&G[i * W + jb * JW + u], acc[a][u]);
    }
}

// ---------------- pure GEMM kernel (R23 structure, 4 blocks/CU) ----------------
__global__ __launch_bounds__(256, 4)
void gemm_kernel(const short* __restrict__ Zs, const short* __restrict__ Es,
                 const float* __restrict__ z2s, const float* __restrict__ e2s,
                 u64* __restrict__ packed,
                 float* __restrict__ candD, int* __restrict__ candN,
                 int* __restrict__ ncand) {
    __shared__ __align__(16) char smem[32768];
    const int tid = threadIdx.x;

    short* As = (short*)smem;                 // [128][64]
    short* Bs = As + 128 * 64;
    const int g = blockIdx.x;
    const int lane = tid & 63, wid = tid >> 6;
    const int wm = wid >> 1, wn = wid & 1;
    const int t0 = (g & 31) * 128, n0 = (g >> 5) * 128;

    f32x4 acc[4][4];
#pragma unroll
    for (int bi = 0; bi < 4; ++bi)
#pragma unroll
        for (int bj = 0; bj < 4; ++bj) {
            f32x4 zz = {0.f, 0.f, 0.f, 0.f};
            acc[bi][bj] = zz;
        }

    auto stage = [&](int k0) {
        const int rb0 = wid * 32;
#pragma unroll
        for (int c2 = 0; c2 < 4; ++c2) {
            int rb = rb0 + c2 * 8;
            int row = rb + (lane >> 3);
            int q = (lane & 7) ^ (lane >> 3);   // XOR-quad swizzle (rb%8==0)
            async_load16(Zs + (size_t)(t0 + row) * KE + k0 + q * 8, &As[rb * 64]);
            async_load16(Es + (size_t)(n0 + row) * KE + k0 + q * 8, &Bs[rb * 64]);
        }
    };
    auto compute_half = [&](int s) {
        bf16x8 bfv[4];
#pragma unroll
        for (int bj = 0; bj < 4; ++bj) {
            int brow = wn * 64 + bj * 16 + (lane & 15);
            int q = ((s << 2) | (lane >> 4)) ^ (brow & 7);
            bfv[bj] = *reinterpret_cast<const bf16x8*>(&Bs[brow * 64 + q * 8]);
        }
#pragma unroll
        for (int bi = 0; bi < 4; ++bi) {
            int arow = wm * 64 + bi * 16 + (lane & 15);
            int q = ((s << 2) | (lane >> 4)) ^ (arow & 7);
            bf16x8 af = *reinterpret_cast<const bf16x8*>(&As[arow * 64 + q * 8]);
#pragma unroll
            for (int bj = 0; bj < 4; ++bj)
                acc[bi][bj] = __builtin_amdgcn_mfma_f32_16x16x32_bf16(
                    af, bfv[bj], acc[bi][bj], 0, 0, 0);
        }
    };

    int k0 = 0;
    for (int r = 0; r < 4; ++r) {
        stage(k0); __syncthreads();
        compute_half(0); compute_half(1);
        __syncthreads(); k0 += 64;
    }

    // ---- epilogue: argmin pass + capture-only pass (R23-exact) ----
    u64*   tokmin = (u64*)smem;               // [128][2]
    float* bthr   = (float*)(smem + 2048);    // [128]

    float e2sv[4];
#pragma unroll
    for (int bj = 0; bj < 4; ++bj)
        e2sv[bj] = e2s[n0 + wn * 64 + bj * 16 + (lane & 15)];

#pragma unroll
    for (int bi = 0; bi < 4; ++bi) {
        u64 pmin[4] = {~0ull, ~0ull, ~0ull, ~0ull};
        f32x4 z4 = *reinterpret_cast<const f32x4*>(
            &z2s[t0 + wm * 64 + bi * 16 + (lane >> 4) * 4]);
#pragma unroll
        for (int reg = 0; reg < 4; ++reg) {
#pragma unroll
            for (int bj = 0; bj < 4; ++bj) {
                float d = z4[reg] + e2sv[bj] + acc[bi][bj][reg];
                int n = n0 + wn * 64 + bj * 16 + (lane & 15);
                u64 pv = (((u64)__float_as_uint(d)) << 32) | (unsigned)n;
                if (pv < pmin[reg]) pmin[reg] = pv;
            }
        }
#pragma unroll
        for (int m = 1; m < 16; m <<= 1)
#pragma unroll
            for (int reg = 0; reg < 4; ++reg) {
                u64 o = __shfl_xor(pmin[reg], m, 64);
                if (o < pmin[reg]) pmin[reg] = o;
            }
        if ((lane & 15) == 0) {
#pragma unroll
            for (int reg = 0; reg < 4; ++reg) {
                int tl = wm * 64 + bi * 16 + (lane >> 4) * 4 + reg;
                tokmin[tl * 2 + wn] = pmin[reg];
            }
        }
    }
    __syncthreads();

    if (tid < 128) {
        int tl = tid;
        u64 bm = tokmin[tl * 2], b1 = tokmin[tl * 2 + 1];
        if (b1 < bm) bm = b1;
        u64 old = atomicMin(&packed[t0 + tl], bm);
        u64 gb = (old < bm) ? old : bm;
        bthr[tl] = __uint_as_float((unsigned)(gb >> 32)) + DCUT;
    }
    __syncthreads();

    // capture pass: ballot-aggregated (16 lanes/token share t).
#pragma unroll
    for (int bi = 0; bi < 4; ++bi) {
        f32x4 z4 = *reinterpret_cast<const f32x4*>(
            &z2s[t0 + wm * 64 + bi * 16 + (lane >> 4) * 4]);
#pragma unroll
        for (int reg = 0; reg < 4; ++reg) {
            int tl = wm * 64 + bi * 16 + (lane >> 4) * 4 + reg;
            int t = t0 + tl;
            float thr = bthr[tl];
#pragma unroll
            for (int bj = 0; bj < 4; ++bj) {
                float d = z4[reg] + e2sv[bj] + acc[bi][bj][reg];
                bool hit = (d <= thr);
                u64 mask = __ballot(hit);
                unsigned gm = (unsigned)((mask >> ((lane >> 4) << 4)) & 0xFFFFu);
                int cnt = __popc(gm);
                if (cnt) {
                    int pos0 = 0;
                    if ((lane & 15) == 0) pos0 = atomicAdd(&ncand[t], cnt);
                    pos0 = __shfl(pos0, (lane >> 4) << 4, 64);
                    if (hit) {
                        int pos = pos0 + __popc(gm & ((1u << (lane & 15)) - 1u));
                        if (pos < CAP) {
                            candD[(size_t)t * CAP + pos] = d;
                            candN[(size_t)t * CAP + pos] = n0 + wn * 64 + bj * 16 + (lane & 15);
                        }
                    }
                }
            }
        }
    }
}

// ---------------- combine + gram + zq + scatter + last-block finalize ----------
// Grid = NGRAM (282 gram/reduce) + NCOMB (256 token blocks x 16 tokens).
// All 538 blocks increment done_ctr; the last one runs finalize.
__global__ __launch_bounds__(256)
void combine_final_kernel(const u64* __restrict__ packed,
                          const float* __restrict__ enorm, const float* __restrict__ znorm,
                          const float* __restrict__ z2s, const float* __restrict__ e2s,
                          float* __restrict__ candD, const int* __restrict__ candN,
                          const int* __restrict__ ncand, float* __restrict__ avg_num,
                          float* __restrict__ scal, int* __restrict__ done_ctr,
                          float* __restrict__ G, float* __restrict__ SV,
                          float* __restrict__ mom,
                          const float* __restrict__ SVeS, const float* __restrict__ SVeV,
                          const float* __restrict__ SVzS, const float* __restrict__ SVzV,
                          const float* __restrict__ mompart,
                          float* __restrict__ out) {
    __shared__ __align__(16) float q_lds[256][17];   // token path; gram xs reuse
    __shared__ float red[256];
    __shared__ float Zts[16], entp[16];
    __shared__ int idxs[16];
    __shared__ int lastf;
    int tid = threadIdx.x;
    int bid = blockIdx.x;

    if (bid < NGRAM) {                       // =========== GRAM path ===========
        int b = bid;
        float* xs = (float*)q_lds;           // 17408B >= 12288B needed
        float* r1 = red;
        float* r2 = (float*)q_lds;

        if (b == 280) {                       // SV reduce
            int c = tid;
            float s = 0.f, v = 0.f;
            for (int j = 0; j < NZB; ++j) { s += SVzS[(size_t)j * 256 + c]; v += SVzV[(size_t)j * 256 + c]; }
            SV[c] = s; SV[256 + c] = v;
            s = 0.f; v = 0.f;
            for (int j = 0; j < NCB; ++j) { s += SVeS[(size_t)j * 256 + c]; v += SVeV[(size_t)j * 256 + c]; }
            SV[512 + c] = s; SV[768 + c] = v;
        } else if (b == 281) {                // moments reduce
            int q = tid & 3, grp = tid >> 2;
            float accE = 0.f, accZ = 0.f;
            for (int j = grp; j < NCB; j += 64) accE += mompart[j * 4 + q];
            for (int j = NCB + grp; j < NCB + NZB; j += 64) accZ += mompart[j * 4 + q];
            r1[tid] = accE; r2[tid] = accZ;
            __syncthreads();
            for (int st = 32; st > 0; st >>= 1) {
                if (grp < st) { r1[tid] += r1[tid + st * 4]; r2[tid] += r2[tid + st * 4]; }
                __syncthreads();
            }
            if (grp == 0) { mom[4 + q] = r1[q]; mom[q] = r2[q]; }
        } else if (b < 192) {
            gram_strip<192>(enorm, G + 4096, (b >> 5) * 32, (b & 31) * 512, 512, 64, xs, tid);
        } else if (b < 224) {
            int l = b - 192;
            gram_strip<64>(enorm, G, (l >> 4) * 32, (l & 15) * 1024, 1024, 0, xs, tid);
        } else if (b < 272) {
            int l = b - 224;
            gram_strip<192>(znorm, G + 45056, (l >> 3) * 32, (l & 7) * 512, 512, 64, xs, tid);
        } else {
            int l = b - 272;
            gram_strip<64>(znorm, G + 40960, (l >> 2) * 32, (l & 3) * 1024, 1024, 0, xs, tid);
        }
    } else {                                  // =========== token path ===========
        int tbase = (bid - NGRAM) * 16;

        // phase 1: softmax stats + exact argmin rescore (16 lanes/token)
        {
            int tok = tid >> 4, sub = tid & 15;
            int tt = tbase + tok;
            u64 pv = packed[tt];
            float dmin = __uint_as_float((unsigned)(pv >> 32));
            float M = -100.f * dmin;
            int nc = min(ncand[tt], CAP);
            size_t base = (size_t)tt * CAP;
            float Zp = 0.f, Wp = 0.f;
            float bestd = 1e30f; int bestn = (int)(pv & 0xFFFFFFFFull);
            for (int i = sub; i < nc; i += 16) {
                float dap = candD[base + i];
                float a = -100.f * dap;
                float e = __expf(a - M);
                candD[base + i] = e;
                Zp += e; Wp = fmaf(a, e, Wp);
                if (dap <= dmin + RTHR) {
                    int n = candN[base + i];
                    const float4* ep = (const float4*)&enorm[(size_t)n * KD];
                    const float4* zp = (const float4*)&znorm[(size_t)tt * KD];
                    float s0 = 0.f, s1 = 0.f, s2 = 0.f, s3 = 0.f;
                    for (int j = 0; j < 64; ++j) {
                        float4 ev = ep[j], zv = zp[j];
                        s0 = fmaf(ev.x, zv.x, s0); s1 = fmaf(ev.y, zv.y, s1);
                        s2 = fmaf(ev.z, zv.z, s2); s3 = fmaf(ev.w, zv.w, s3);
                    }
                    float dex = z2s[tt] + e2s[n] - 2.f * ((s0 + s1) + (s2 + s3));
                    if (dex < bestd) { bestd = dex; bestn = n; }
                }
            }
            u64 pb = (((u64)__float_as_uint(bestd)) << 32) | (unsigned)bestn;
#pragma unroll
            for (int m = 1; m < 16; m <<= 1) {
                Zp += __shfl_xor(Zp, m, 64);
                Wp += __shfl_xor(Wp, m, 64);
                u64 o = __shfl_xor(pb, m, 64);
                if (o < pb) pb = o;
            }
            if (sub == 0) {
                Zts[tok] = Zp;
                int idx = (int)(pb & 0xFFFFFFFFull);
                idxs[tok] = idx;
                out[1048581 + tt] = (float)idx;
                entp[tok] = M + logf(Zp) - Wp / Zp;
            }
        }
        __syncthreads();
        if (tid == 0) {
            float ent = 0.f;
#pragma unroll
            for (int i = 0; i < 16; ++i) ent += entp[i];
            atomicAdd(&scal[3], ent);
        }

        // phase 2: z_q gather + transpose + vq loss (16 tokens)
        float sdq = 0.f;
        for (int tl2 = 0; tl2 < 16; ++tl2) {
            int tt = tbase + tl2;
            float qv = enorm[(size_t)idxs[tl2] * KD + tid];
            q_lds[tid][tl2] = qv;
            float zc = znorm[(size_t)tt * KD + tid];
            float df = qv - zc;
            sdq = fmaf(df, df, sdq);
        }
        __syncthreads();
        {
            int bb = tbase >> 10, hw0 = tbase & 1023;
            int cg = tid >> 4, hwl = tid & 15;
            for (int c0 = 0; c0 < 256; c0 += 16) {
                int c = c0 + cg;
                out[(((size_t)(bb * 256 + c)) << 10) + hw0 + hwl] = q_lds[c][hwl];
            }
        }
        red[tid] = sdq;
        __syncthreads();
        for (int s = 128; s > 0; s >>= 1) { if (tid < s) red[tid] += red[tid + s]; __syncthreads(); }
        if (tid == 0) atomicAdd(&scal[2], red[0]);

        // phase 3: avg_probs scatter (cached e / Zt)
        {
            int tok = tid >> 4, sub = tid & 15;
            int tt = tbase + tok;
            int nc = min(ncand[tt], CAP);
            float rZ = 1.f / Zts[tok];
            for (int i = sub; i < nc; i += 16) {
                atomicAdd(&avg_num[candN[(size_t)tt * CAP + i]],
                          candD[(size_t)tt * CAP + i] * rZ);
            }
        }
    }

    // ---- finalize gate: last of all NGRAM+NCOMB blocks runs finalize ----
    __syncthreads();
    __threadfence();
    if (tid == 0) lastf = (atomicAdd(done_ctr, 1) == (NGRAM + NCOMB - 1)) ? 1 : 0;
    __syncthreads();
    if (!lastf) return;
    __threadfence();

    float s = 0.f;
#pragma unroll 4
    for (int n = tid; n < NE; n += 256) {
        float avg = atomicAdd(&avg_num[n], 0.f) * (1.f / 4096.f);
        s += avg * logf(avg + 1e-5f);
    }
    red[tid] = s; __syncthreads();
    for (int st = 128; st > 0; st >>= 1) { if (tid < st) red[tid] += red[tid + st]; __syncthreads(); }
    float avg_ent_neg = red[0];
    __syncthreads();

    const float* G_ek = G;
    const float* G_eg = G + 4096;
    const float* G_zk = G + 40960;
    const float* G_zg = G + 45056;
    float rk = 0.f, rg = 0.f;
#pragma unroll 4
    for (int i = tid; i < 4096; i += 256)  rk = fmaf(G_zk[i], G_ek[i], rk);
#pragma unroll 4
    for (int i = tid; i < 36864; i += 256) rg = fmaf(G_zg[i], G_eg[i], rg);
    {
        int c = tid;
        float v = SV[256 + c] * SV[512 + c] + SV[c] * SV[768 + c];
        if (c < 64) rk -= v; else rg -= v;
    }
    red[tid] = 4.f * rk; __syncthreads();
    for (int st = 128; st > 0; st >>= 1) { if (tid < st) red[tid] += red[tid + st]; __syncthreads(); }
    float red_k = red[0];
    __syncthreads();
    red[tid] = 4.f * rg; __syncthreads();
    for (int st = 128; st > 0; st >>= 1) { if (tid < st) red[tid] += red[tid + st]; __syncthreads(); }
    float red_g = red[0];

    if (tid == 0) {
        float term1k = NE * mom[1] + 2.f * mom[0] * mom[4] + T_TOK * mom[5];
        float term1g = NE * mom[3] + 2.f * mom[2] * mom[6] + T_TOK * mom[7];
        float sdk2 = term1k + red_k;
        float sdg2 = term1g + red_g;
        float avg_ent = -avg_ent_neg;
        float se = atomicAdd(&scal[3], 0.f) * (1.f / 4096.f);
        float vq = atomicAdd(&scal[2], 0.f) * (1.f / 1048576.f);
        out[1048576] = vq;
        out[1048577] = 0.25f * vq;
        out[1048578] = 0.1f * (se - avg_ent);
        out[1048579] = sdk2 * (1.f / 4096.f);
        out[1048580] = sdg2 * (1.f / 4096.f);
    }
}

// ---------------- host ----------------
extern "C" void kernel_launch(void* const* d_in, const int* in_sizes, int n_in,
                              void* d_out, int out_size, void* d_ws, size_t ws_size,
                              hipStream_t stream) {
    const float* z  = (const float*)d_in[0];
    const float* wk = (const float*)d_in[1];
    const float* wg = (const float*)d_in[2];
    float* out = (float*)d_out;

    char* ws = (char*)d_ws;
    size_t off = 0;
    auto alloc = [&](size_t bytes) {
        void* p = ws + off;
        off += (bytes + 255) & ~(size_t)255;
        return p;
    };
    float* enorm  = (float*)alloc((size_t)NE * KD * 4);
    float* znorm  = (float*)alloc((size_t)T_TOK * KD * 4);
    short* Es     = (short*)alloc((size_t)NE * KE * 2);
    short* Zs     = (short*)alloc((size_t)T_TOK * KE * 2);
    float* e2k    = (float*)alloc(NE * 4);
    float* e2s    = (float*)alloc(NE * 4);
    float* z2k    = (float*)alloc(T_TOK * 4);
    float* z2s    = (float*)alloc(T_TOK * 4);
    u64*   packed = (u64*)alloc(T_TOK * 8);
    int*   ncand  = (int*)alloc(T_TOK * 4);
    float* candD  = (float*)alloc((size_t)T_TOK * CAP * 4);
    int*   candN  = (int*)alloc((size_t)T_TOK * CAP * 4);
    float* avg_num= (float*)alloc(NE * 4);
    float* scal   = (float*)alloc(8 * 4);
    float* Gbuf   = (float*)alloc(81920 * 4);
    float* SV     = (float*)alloc(1024 * 4);
    float* momv   = (float*)alloc(8 * 4);
    float* SVeS   = (float*)alloc((size_t)NCB * 256 * 4);
    float* SVeV   = (float*)alloc((size_t)NCB * 256 * 4);
    float* SVzS   = (float*)alloc((size_t)NZB * 256 * 4);
    float* SVzV   = (float*)alloc((size_t)NZB * 256 * 4);
    float* mompart= (float*)alloc((size_t)(NCB + NZB) * 4 * 4);
    int*   done_ctr = (int*)alloc(256);

    megaprep_kernel<<<NCB + NZB + 8, 256, 0, stream>>>(
        wk, wg, z, enorm, e2k, e2s, Es, znorm, z2k, z2s, Zs,
        SVeS, SVeV, SVzS, SVzV, mompart, packed, avg_num, ncand, scal, Gbuf, done_ctr);

    gemm_kernel<<<NGEMM, 256, 0, stream>>>(
        Zs, Es, z2s, e2s, packed, candD, candN, ncand);

    combine_final_kernel<<<NGRAM + NCOMB, 256, 0, stream>>>(
        packed, enorm, znorm, z2s, e2s,
        candD, candN, ncand, avg_num, scal, done_ctr,
        Gbuf, SV, momv, SVeS, SVeV, SVzS, SVzV, mompart, out);
}

// Round 13
// 274.715 us; speedup vs baseline: 1.1663x; 1.1663x over previous
//
#include <hip/hip_runtime.h>

// VectorQuantizer forward, MI355X. R26 = R23-exact revert (verified best,
// 283.7us). R25's gram->combine move serialized gram after the GEMM
// (combine ballooned to 151us, +LDS bank conflicts from xs/q_lds aliasing);
// reverted. Ledger: wins are R20 (single-product KE=256 + fp32 rescore) and
// R23 (ballot capture + finer gram strips, spill-free (256,4)); all
// structural rearrangements (pipelining, register-direct, L2 remaps,
// n-loop blocks, occupancy 5/CU, select-argmin, kernel re-partition)
// regressed. Config: fused gram+GEMM kernel (282 gram jobs ride under 4096
// gemm blocks), 2-phase BK=64 loop, 32KB LDS, XOR-quad swizzle, u64-packed
// argmin + atomicMin threshold, ballot-aggregated DCUT=0.13 capture;
// combine 256x16 tokens: entropy from candidates + exact fp32 argmin
// rescore (RTHR) + z_q scatter + closed-form d^2-norm finalize.
// 3 kernels. T=4096, NE=16384.

#define T_TOK 4096
#define NE    16384
#define KD    256
#define KE    256          // single-product K
#define CAP   1024         // candidate slots per token
#define DCUT  0.13f        // capture window above best-so-far global min
#define RTHR  0.004f       // exact-rescore window above approx min

#define NCB   512          // code prep blocks (32 rows each)
#define NZB   128          // z prep blocks (32 tokens each)
#define NGRAM 282          // 280 gram strip jobs + 2 reduce blocks
#define NGEMM 4096         // gemm blocks (32 x 128)

typedef __attribute__((ext_vector_type(8))) short bf16x8;
typedef __attribute__((ext_vector_type(4))) float f32x4;
typedef unsigned long long u64;

__device__ __forceinline__ short f2bf(float f) {
    unsigned u = __float_as_uint(f);
    u = (u + 0x7FFFu + ((u >> 16) & 1u)) >> 16;   // round-to-nearest-even
    return (short)u;
}
__device__ __forceinline__ float bf2f(short s) {
    return __uint_as_float(((unsigned)(unsigned short)s) << 16);
}

__device__ __forceinline__ void async_load16(const void* g, void* l) {
    __builtin_amdgcn_global_load_lds(
        (const __attribute__((address_space(1))) void*)g,
        (__attribute__((address_space(3))) void*)l, 16, 0, 0);
}

// ---------------- megaprep: codes | z | init, branch on blockIdx ---------
__global__ __launch_bounds__(256)
void megaprep_kernel(const float* __restrict__ wk, const float* __restrict__ wg,
                     const float* __restrict__ z,
                     float* __restrict__ enorm, float* __restrict__ e2k,
                     float* __restrict__ e2s, short* __restrict__ Es,
                     float* __restrict__ znorm, float* __restrict__ z2k,
                     float* __restrict__ z2s, short* __restrict__ Zs,
                     float* __restrict__ SVeS, float* __restrict__ SVeV,
                     float* __restrict__ SVzS, float* __restrict__ SVzV,
                     float* __restrict__ mompart,
                     u64* __restrict__ packed, float* __restrict__ avg_num,
                     int* __restrict__ ncand, float* __restrict__ scal,
                     float* __restrict__ G, int* __restrict__ done_ctr) {
    int b = blockIdx.x, tid = threadIdx.x;
    if (b >= NCB + NZB) {                    // ---- init branch ----
        int gid = (b - NCB - NZB) * 256 + tid;
        for (int i = gid; i < 81920; i += 2048) G[i] = 0.f;
        for (int i = gid; i < NE; i += 2048) avg_num[i] = 0.f;
        for (int i = gid; i < T_TOK; i += 2048) { packed[i] = ~0ull; ncand[i] = 0; }
        if (gid < 8) scal[gid] = 0.f;
        if (gid == 8) *done_ctr = 0;
        return;
    }

    __shared__ float xs[32][257];            // 32.9 KB
    __shared__ float ps[32][8];
    __shared__ float rnorm[32][2];
    __shared__ float rw[32][2];

    if (b < NCB) {                           // ---- codes branch ----
        int n0 = b * 32;
#pragma unroll
        for (int i = 0; i < 8; ++i) {
            int idx = tid + i * 256;
            xs[idx >> 6][idx & 63] = wk[(size_t)n0 * 64 + idx];
        }
#pragma unroll
        for (int i = 0; i < 24; ++i) {
            int idx = tid + i * 256;
            xs[idx / 192][64 + idx % 192] = wg[(size_t)n0 * 192 + idx];
        }
        __syncthreads();
        {
            int r = tid & 31, part = tid >> 5;
            float s = 0.f;
            for (int j = 0; j < 32; ++j) { float v = xs[r][part * 32 + j]; s = fmaf(v, v, s); }
            ps[r][part] = s;
        }
        __syncthreads();
        if (tid < 32) {
            float sk = ps[tid][0] + ps[tid][1];
            float sg = ps[tid][2] + ps[tid][3] + ps[tid][4] + ps[tid][5] + ps[tid][6] + ps[tid][7];
            float nk = fmaxf(sqrtf(sk), 1e-12f), ng = fmaxf(sqrtf(sg), 1e-12f);
            float ek2 = sk / (nk * nk), eg2 = sg / (ng * ng);
            rnorm[tid][0] = 1.f / nk; rnorm[tid][1] = 1.f / ng;
            rw[tid][0] = ek2; rw[tid][1] = eg2;
            e2k[n0 + tid] = ek2; e2s[n0 + tid] = ek2 + eg2;
        }
        __syncthreads();
        int c = tid;
        for (int i = 0; i < 32; ++i) {
            float y = xs[i][c] * rnorm[i][(c < 64) ? 0 : 1];
            enorm[(size_t)(n0 + i) * KD + c] = y;
            Es[(size_t)(n0 + i) * KE + c] = f2bf(-2.f * y);
        }
        {
            int sel = (c < 64) ? 0 : 1;
            float S = 0.f, V = 0.f;
            for (int r = 0; r < 32; ++r) {
                float y = xs[r][c] * rnorm[r][sel];
                S += y; V = fmaf(rw[r][sel], y, V);
            }
            SVeS[(size_t)b * 256 + c] = S;
            SVeV[(size_t)b * 256 + c] = V;
        }
        if (tid < 32) {
            float a = rw[tid][0], g = rw[tid][1];
            float s0 = a, s1 = a * a, s2 = g, s3 = g * g;
#pragma unroll
            for (int m = 1; m < 32; m <<= 1) {
                s0 += __shfl_xor(s0, m, 64); s1 += __shfl_xor(s1, m, 64);
                s2 += __shfl_xor(s2, m, 64); s3 += __shfl_xor(s3, m, 64);
            }
            if (tid == 0) {
                mompart[b * 4 + 0] = s0; mompart[b * 4 + 1] = s1;
                mompart[b * 4 + 2] = s2; mompart[b * 4 + 3] = s3;
            }
        }
    } else {                                 // ---- z branch ----
        int jz = b - NCB;
        int t0 = jz * 32;
        int bb = t0 >> 10, hw0 = t0 & 1023;
#pragma unroll
        for (int i = 0; i < 32; ++i) {
            int idx = tid + i * 256;
            int cc = idx >> 5, hwl = idx & 31;
            xs[hwl][cc] = z[(((size_t)bb * 256 + cc) << 10) + hw0 + hwl];
        }
        __syncthreads();
        {
            int r = tid & 31, part = tid >> 5;
            float s = 0.f;
            for (int j = 0; j < 32; ++j) { float v = xs[r][part * 32 + j]; s = fmaf(v, v, s); }
            ps[r][part] = s;
        }
        __syncthreads();
        if (tid < 32) {
            float sk = ps[tid][0] + ps[tid][1];
            float sg = ps[tid][2] + ps[tid][3] + ps[tid][4] + ps[tid][5] + ps[tid][6] + ps[tid][7];
            float nk = fmaxf(sqrtf(sk), 1e-12f), ng = fmaxf(sqrtf(sg), 1e-12f);
            float zk2 = sk / (nk * nk), zg2 = sg / (ng * ng);
            rnorm[tid][0] = 1.f / nk; rnorm[tid][1] = 1.f / ng;
            rw[tid][0] = zk2; rw[tid][1] = zg2;
            z2k[t0 + tid] = zk2; z2s[t0 + tid] = zk2 + zg2;
        }
        __syncthreads();
        int c = tid;
        for (int i = 0; i < 32; ++i) {
            float y = xs[i][c] * rnorm[i][(c < 64) ? 0 : 1];
            znorm[(size_t)(t0 + i) * KD + c] = y;
            Zs[(size_t)(t0 + i) * KE + c] = f2bf(y);
        }
        {
            int sel = (c < 64) ? 0 : 1;
            float S = 0.f, V = 0.f;
            for (int r = 0; r < 32; ++r) {
                float y = xs[r][c] * rnorm[r][sel];
                S += y; V = fmaf(rw[r][sel], y, V);
            }
            SVzS[(size_t)jz * 256 + c] = S;
            SVzV[(size_t)jz * 256 + c] = V;
        }
        if (tid < 32) {
            float a = rw[tid][0], g = rw[tid][1];
            float s0 = a, s1 = a * a, s2 = g, s3 = g * g;
#pragma unroll
            for (int m = 1; m < 32; m <<= 1) {
                s0 += __shfl_xor(s0, m, 64); s1 += __shfl_xor(s1, m, 64);
                s2 += __shfl_xor(s2, m, 64); s3 += __shfl_xor(s3, m, 64);
            }
            if (tid == 0) {
                mompart[b * 4 + 0] = s0; mompart[b * 4 + 1] = s1;
                mompart[b * 4 + 2] = s2; mompart[b * 4 + 3] = s3;
            }
        }
    }
}

// ---------------- gram strip job: 32-col i-strip x full W, register acc --------
template <int W>
__device__ __forceinline__ void gram_strip(const float* __restrict__ X, float* __restrict__ G,
                                           int i0s, int r0, int rows, int c0,
                                           float* xs, int tid) {
    const int JW = W / 32;                    // 6 (W=192) or 2 (W=64)
    int ia = tid >> 5;
    int jb = tid & 31;
    float acc[4][JW];
#pragma unroll
    for (int a = 0; a < 4; ++a)
#pragma unroll
        for (int u = 0; u < JW; ++u) acc[a][u] = 0.f;
    for (int rb = 0; rb < rows; rb += 16) {
        __syncthreads();
        for (int lin = tid; lin < 4 * W; lin += 256) {
            int r = lin / (W / 4), f4 = lin % (W / 4);
            *(float4*)&xs[r * W + f4 * 4] =
                *(const float4*)&X[(size_t)(r0 + rb + r) * KD + c0 + f4 * 4];
        }
        __syncthreads();
#pragma unroll 4
        for (int r = 0; r < 16; ++r) {
            float4 xi = *(const float4*)&xs[r * W + i0s + ia * 4];
            float xj[JW];
#pragma unroll
            for (int u = 0; u < JW; ++u) xj[u] = xs[r * W + jb * JW + u];
#pragma unroll
            for (int a = 0; a < 4; ++a)
#pragma unroll
                for (int u = 0; u < JW; ++u)
                    acc[a][u] = fmaf(xi[a], xj[u], acc[a][u]);
        }
    }
#pragma unroll
    for (int a = 0; a < 4; ++a) {
        int i = i0s + ia * 4 + a;
#pragma unroll
        for (int u = 0; u < JW; ++u)
            atomicAdd(&G[i * W + jb * JW + u], acc[a][u]);
    }
}

// ---------------- fused Gram (HEAD) + GEMM (4 blocks/CU) --------
__global__ __launch_bounds__(256, 4)
void gemm_gram_kernel(const short* __restrict__ Zs, const short* __restrict__ Es,
                      const float* __restrict__ z2s, const float* __restrict__ e2s,
                      u64* __restrict__ packed,
                      float* __restrict__ candD, int* __restrict__ candN,
                      int* __restrict__ ncand,
                      const float* __restrict__ znorm, const float* __restrict__ enorm,
                      float* __restrict__ Gbuf,
                      const float* __restrict__ SVeS, const float* __restrict__ SVeV,
                      const float* __restrict__ SVzS, const float* __restrict__ SVzV,
                      const float* __restrict__ mompart,
                      float* __restrict__ SV, float* __restrict__ mom) {
    __shared__ __align__(16) char smem[32768];
    const int gid = blockIdx.x, tid = threadIdx.x;

    if (gid < NGRAM) {                        // =============== GRAM path ===============
        int b = gid;
        float* xs = (float*)smem;
        float* r1 = (float*)(smem + 12288);
        float* r2 = (float*)(smem + 13312);

        if (b == 280) {                       // SV reduce
            int c = tid;
            float s = 0.f, v = 0.f;
            for (int j = 0; j < NZB; ++j) { s += SVzS[(size_t)j * 256 + c]; v += SVzV[(size_t)j * 256 + c]; }
            SV[c] = s; SV[256 + c] = v;
            s = 0.f; v = 0.f;
            for (int j = 0; j < NCB; ++j) { s += SVeS[(size_t)j * 256 + c]; v += SVeV[(size_t)j * 256 + c]; }
            SV[512 + c] = s; SV[768 + c] = v;
            return;
        }
        if (b == 281) {                       // moments reduce
            int q = tid & 3, grp = tid >> 2;
            float accE = 0.f, accZ = 0.f;
            for (int j = grp; j < NCB; j += 64) accE += mompart[j * 4 + q];
            for (int j = NCB + grp; j < NCB + NZB; j += 64) accZ += mompart[j * 4 + q];
            r1[tid] = accE; r2[tid] = accZ;
            __syncthreads();
            for (int st = 32; st > 0; st >>= 1) {
                if (grp < st) { r1[tid] += r1[tid + st * 4]; r2[tid] += r2[tid + st * 4]; }
                __syncthreads();
            }
            if (grp == 0) { mom[4 + q] = r1[q]; mom[q] = r2[q]; }
            return;
        }
        // strips (2x finer):
        // [0,192)   E-g: 6 i-strips x 32 row-chunks of 512
        // [192,224) E-k: 2 i-strips x 16 row-chunks of 1024
        // [224,272) Z-g: 6 i-strips x 8 row-chunks of 512
        // [272,280) Z-k: 2 i-strips x 4 row-chunks of 1024
        if (b < 192) {
            gram_strip<192>(enorm, Gbuf + 4096, (b >> 5) * 32, (b & 31) * 512, 512, 64, xs, tid);
        } else if (b < 224) {
            int l = b - 192;
            gram_strip<64>(enorm, Gbuf, (l >> 4) * 32, (l & 15) * 1024, 1024, 0, xs, tid);
        } else if (b < 272) {
            int l = b - 224;
            gram_strip<192>(znorm, Gbuf + 45056, (l >> 3) * 32, (l & 7) * 512, 512, 64, xs, tid);
        } else {
            int l = b - 272;
            gram_strip<64>(znorm, Gbuf + 40960, (l >> 2) * 32, (l & 3) * 1024, 1024, 0, xs, tid);
        }
        return;
    }

    // =============== GEMM path ===============
    short* As = (short*)smem;                 // [128][64]
    short* Bs = As + 128 * 64;
    const int g = gid - NGRAM;
    const int lane = tid & 63, wid = tid >> 6;
    const int wm = wid >> 1, wn = wid & 1;
    const int t0 = (g & 31) * 128, n0 = (g >> 5) * 128;

    f32x4 acc[4][4];
#pragma unroll
    for (int bi = 0; bi < 4; ++bi)
#pragma unroll
        for (int bj = 0; bj < 4; ++bj) {
            f32x4 zz = {0.f, 0.f, 0.f, 0.f};
            acc[bi][bj] = zz;
        }

    auto stage = [&](int k0) {
        const int rb0 = wid * 32;
#pragma unroll
        for (int c2 = 0; c2 < 4; ++c2) {
            int rb = rb0 + c2 * 8;
            int row = rb + (lane >> 3);
            int q = (lane & 7) ^ (lane >> 3);   // XOR-quad swizzle (rb%8==0)
            async_load16(Zs + (size_t)(t0 + row) * KE + k0 + q * 8, &As[rb * 64]);
            async_load16(Es + (size_t)(n0 + row) * KE + k0 + q * 8, &Bs[rb * 64]);
        }
    };
    auto compute_half = [&](int s) {
        bf16x8 bfv[4];
#pragma unroll
        for (int bj = 0; bj < 4; ++bj) {
            int brow = wn * 64 + bj * 16 + (lane & 15);
            int q = ((s << 2) | (lane >> 4)) ^ (brow & 7);
            bfv[bj] = *reinterpret_cast<const bf16x8*>(&Bs[brow * 64 + q * 8]);
        }
#pragma unroll
        for (int bi = 0; bi < 4; ++bi) {
            int arow = wm * 64 + bi * 16 + (lane & 15);
            int q = ((s << 2) | (lane >> 4)) ^ (arow & 7);
            bf16x8 af = *reinterpret_cast<const bf16x8*>(&As[arow * 64 + q * 8]);
#pragma unroll
            for (int bj = 0; bj < 4; ++bj)
                acc[bi][bj] = __builtin_amdgcn_mfma_f32_16x16x32_bf16(
                    af, bfv[bj], acc[bi][bj], 0, 0, 0);
        }
    };

    int k0 = 0;
    for (int r = 0; r < 4; ++r) {
        stage(k0); __syncthreads();
        compute_half(0); compute_half(1);
        __syncthreads(); k0 += 64;
    }

    // ---- epilogue: argmin pass + capture-only pass ----
    u64*   tokmin = (u64*)smem;               // [128][2]
    float* bthr   = (float*)(smem + 2048);    // [128]

    float e2sv[4];
#pragma unroll
    for (int bj = 0; bj < 4; ++bj)
        e2sv[bj] = e2s[n0 + wn * 64 + bj * 16 + (lane & 15)];

#pragma unroll
    for (int bi = 0; bi < 4; ++bi) {
        u64 pmin[4] = {~0ull, ~0ull, ~0ull, ~0ull};
        f32x4 z4 = *reinterpret_cast<const f32x4*>(
            &z2s[t0 + wm * 64 + bi * 16 + (lane >> 4) * 4]);
#pragma unroll
        for (int reg = 0; reg < 4; ++reg) {
#pragma unroll
            for (int bj = 0; bj < 4; ++bj) {
                float d = z4[reg] + e2sv[bj] + acc[bi][bj][reg];
                int n = n0 + wn * 64 + bj * 16 + (lane & 15);
                u64 pv = (((u64)__float_as_uint(d)) << 32) | (unsigned)n;
                if (pv < pmin[reg]) pmin[reg] = pv;
            }
        }
#pragma unroll
        for (int m = 1; m < 16; m <<= 1)
#pragma unroll
            for (int reg = 0; reg < 4; ++reg) {
                u64 o = __shfl_xor(pmin[reg], m, 64);
                if (o < pmin[reg]) pmin[reg] = o;
            }
        if ((lane & 15) == 0) {
#pragma unroll
            for (int reg = 0; reg < 4; ++reg) {
                int tl = wm * 64 + bi * 16 + (lane >> 4) * 4 + reg;
                tokmin[tl * 2 + wn] = pmin[reg];
            }
        }
    }
    __syncthreads();

    if (tid < 128) {
        int tl = tid;
        u64 bm = tokmin[tl * 2], b1 = tokmin[tl * 2 + 1];
        if (b1 < bm) bm = b1;
        u64 old = atomicMin(&packed[t0 + tl], bm);
        u64 gb = (old < bm) ? old : bm;
        bthr[tl] = __uint_as_float((unsigned)(gb >> 32)) + DCUT;
    }
    __syncthreads();

    // capture pass: any d within DCUT of best-so-far global min.
    // 16 lanes (same lane>>4 group) share token t -> ballot-aggregate:
    // leader does ONE atomicAdd(cnt), lanes take prefix positions ->
    // 16x fewer atomics + contiguous candD/candN stores.
#pragma unroll
    for (int bi = 0; bi < 4; ++bi) {
        f32x4 z4 = *reinterpret_cast<const f32x4*>(
            &z2s[t0 + wm * 64 + bi * 16 + (lane >> 4) * 4]);
#pragma unroll
        for (int reg = 0; reg < 4; ++reg) {
            int tl = wm * 64 + bi * 16 + (lane >> 4) * 4 + reg;
            int t = t0 + tl;
            float thr = bthr[tl];
#pragma unroll
            for (int bj = 0; bj < 4; ++bj) {
                float d = z4[reg] + e2sv[bj] + acc[bi][bj][reg];
                bool hit = (d <= thr);
                u64 mask = __ballot(hit);
                unsigned gm = (unsigned)((mask >> ((lane >> 4) << 4)) & 0xFFFFu);
                int cnt = __popc(gm);
                if (cnt) {
                    int pos0 = 0;
                    if ((lane & 15) == 0) pos0 = atomicAdd(&ncand[t], cnt);
                    pos0 = __shfl(pos0, (lane >> 4) << 4, 64);
                    if (hit) {
                        int pos = pos0 + __popc(gm & ((1u << (lane & 15)) - 1u));
                        if (pos < CAP) {
                            candD[(size_t)t * CAP + pos] = d;
                            candN[(size_t)t * CAP + pos] = n0 + wn * 64 + bj * 16 + (lane & 15);
                        }
                    }
                }
            }
        }
    }
}

// ---------------- combine + zq + scatter + last-block finalize ----------------
// 256 blocks x 16 tokens. Per-token approx-min/M from packed[]; exact argmin
// rescored in fp32 over candidates within RTHR. Z/W/entropy from candidate
// list; exp() cached in candD between phases.
__global__ __launch_bounds__(256)
void combine_final_kernel(const u64* __restrict__ packed,
                          const float* __restrict__ enorm, const float* __restrict__ znorm,
                          const float* __restrict__ z2s, const float* __restrict__ e2s,
                          float* __restrict__ candD, const int* __restrict__ candN,
                          const int* __restrict__ ncand, float* __restrict__ avg_num,
                          float* __restrict__ scal, int* __restrict__ done_ctr,
                          const float* __restrict__ G, const float* __restrict__ SV,
                          const float* __restrict__ mom, float* __restrict__ out) {
    __shared__ float Zts[16], entp[16];
    __shared__ int idxs[16];
    __shared__ float q_lds[256][17];
    __shared__ float red[256];
    __shared__ int lastf;
    int tid = threadIdx.x;
    int tbase = blockIdx.x * 16;

    // phase 1: per-token softmax stats + exact argmin rescore (16 lanes/token)
    {
        int tok = tid >> 4, sub = tid & 15;
        int tt = tbase + tok;
        u64 pv = packed[tt];
        float dmin = __uint_as_float((unsigned)(pv >> 32));
        float M = -100.f * dmin;
        int nc = min(ncand[tt], CAP);
        size_t base = (size_t)tt * CAP;
        float Zp = 0.f, Wp = 0.f;
        float bestd = 1e30f; int bestn = (int)(pv & 0xFFFFFFFFull);
        for (int i = sub; i < nc; i += 16) {
            float dap = candD[base + i];
            float a = -100.f * dap;
            float e = __expf(a - M);
            candD[base + i] = e;
            Zp += e; Wp = fmaf(a, e, Wp);
            if (dap <= dmin + RTHR) {
                // exact fp32 rescore: d = z2 + e2 - 2*dot(znorm, enorm)
                int n = candN[base + i];
                const float4* ep = (const float4*)&enorm[(size_t)n * KD];
                const float4* zp = (const float4*)&znorm[(size_t)tt * KD];
                float s0 = 0.f, s1 = 0.f, s2 = 0.f, s3 = 0.f;
                for (int j = 0; j < 64; ++j) {
                    float4 ev = ep[j], zv = zp[j];
                    s0 = fmaf(ev.x, zv.x, s0); s1 = fmaf(ev.y, zv.y, s1);
                    s2 = fmaf(ev.z, zv.z, s2); s3 = fmaf(ev.w, zv.w, s3);
                }
                float dex = z2s[tt] + e2s[n] - 2.f * ((s0 + s1) + (s2 + s3));
                if (dex < bestd) { bestd = dex; bestn = n; }
            }
        }
        u64 pb = (((u64)__float_as_uint(bestd)) << 32) | (unsigned)bestn;
#pragma unroll
        for (int m = 1; m < 16; m <<= 1) {
            Zp += __shfl_xor(Zp, m, 64);
            Wp += __shfl_xor(Wp, m, 64);
            u64 o = __shfl_xor(pb, m, 64);
            if (o < pb) pb = o;
        }
        if (sub == 0) {
            Zts[tok] = Zp;
            int idx = (int)(pb & 0xFFFFFFFFull);
            idxs[tok] = idx;
            out[1048581 + tt] = (float)idx;
            entp[tok] = M + logf(Zp) - Wp / Zp;
        }
    }
    __syncthreads();
    if (tid == 0) {
        float ent = 0.f;
#pragma unroll
        for (int i = 0; i < 16; ++i) ent += entp[i];
        atomicAdd(&scal[3], ent);
    }

    // phase 2: z_q gather + transpose + vq loss (16 tokens)
    float sdq = 0.f;
    for (int tl2 = 0; tl2 < 16; ++tl2) {
        int tt = tbase + tl2;
        float qv = enorm[(size_t)idxs[tl2] * KD + tid];
        q_lds[tid][tl2] = qv;
        float zc = znorm[(size_t)tt * KD + tid];
        float df = qv - zc;
        sdq = fmaf(df, df, sdq);
    }
    __syncthreads();
    {
        int bb = tbase >> 10, hw0 = tbase & 1023;
        int cg = tid >> 4, hwl = tid & 15;
        for (int c0 = 0; c0 < 256; c0 += 16) {
            int c = c0 + cg;
            out[(((size_t)(bb * 256 + c)) << 10) + hw0 + hwl] = q_lds[c][hwl];
        }
    }
    red[tid] = sdq;
    __syncthreads();
    for (int s = 128; s > 0; s >>= 1) { if (tid < s) red[tid] += red[tid + s]; __syncthreads(); }
    if (tid == 0) atomicAdd(&scal[2], red[0]);

    // phase 3: avg_probs scatter (cached e / Zt)
    {
        int tok = tid >> 4, sub = tid & 15;
        int tt = tbase + tok;
        int nc = min(ncand[tt], CAP);
        float rZ = 1.f / Zts[tok];
        for (int i = sub; i < nc; i += 16) {
            atomicAdd(&avg_num[candN[(size_t)tt * CAP + i]],
                      candD[(size_t)tt * CAP + i] * rZ);
        }
    }

    // phase 4: last block does finalize
    __syncthreads();
    __threadfence();
    if (tid == 0) lastf = (atomicAdd(done_ctr, 1) == 255) ? 1 : 0;
    __syncthreads();
    if (!lastf) return;
    __threadfence();

    float s = 0.f;
#pragma unroll 4
    for (int n = tid; n < NE; n += 256) {
        float avg = atomicAdd(&avg_num[n], 0.f) * (1.f / 4096.f);
        s += avg * logf(avg + 1e-5f);
    }
    red[tid] = s; __syncthreads();
    for (int st = 128; st > 0; st >>= 1) { if (tid < st) red[tid] += red[tid + st]; __syncthreads(); }
    float avg_ent_neg = red[0];
    __syncthreads();

    const float* G_ek = G;
    const float* G_eg = G + 4096;
    const float* G_zk = G + 40960;
    const float* G_zg = G + 45056;
    float rk = 0.f, rg = 0.f;
#pragma unroll 4
    for (int i = tid; i < 4096; i += 256)  rk = fmaf(G_zk[i], G_ek[i], rk);
#pragma unroll 4
    for (int i = tid; i < 36864; i += 256) rg = fmaf(G_zg[i], G_eg[i], rg);
    {
        int c = tid;
        float v = SV[256 + c] * SV[512 + c] + SV[c] * SV[768 + c];
        if (c < 64) rk -= v; else rg -= v;
    }
    red[tid] = 4.f * rk; __syncthreads();
    for (int st = 128; st > 0; st >>= 1) { if (tid < st) red[tid] += red[tid + st]; __syncthreads(); }
    float red_k = red[0];
    __syncthreads();
    red[tid] = 4.f * rg; __syncthreads();
    for (int st = 128; st > 0; st >>= 1) { if (tid < st) red[tid] += red[tid + st]; __syncthreads(); }
    float red_g = red[0];

    if (tid == 0) {
        float term1k = NE * mom[1] + 2.f * mom[0] * mom[4] + T_TOK * mom[5];
        float term1g = NE * mom[3] + 2.f * mom[2] * mom[6] + T_TOK * mom[7];
        float sdk2 = term1k + red_k;
        float sdg2 = term1g + red_g;
        float avg_ent = -avg_ent_neg;
        float se = atomicAdd(&scal[3], 0.f) * (1.f / 4096.f);
        float vq = atomicAdd(&scal[2], 0.f) * (1.f / 1048576.f);
        out[1048576] = vq;
        out[1048577] = 0.25f * vq;
        out[1048578] = 0.1f * (se - avg_ent);
        out[1048579] = sdk2 * (1.f / 4096.f);
        out[1048580] = sdg2 * (1.f / 4096.f);
    }
}

// ---------------- host ----------------
extern "C" void kernel_launch(void* const* d_in, const int* in_sizes, int n_in,
                              void* d_out, int out_size, void* d_ws, size_t ws_size,
                              hipStream_t stream) {
    const float* z  = (const float*)d_in[0];
    const float* wk = (const float*)d_in[1];
    const float* wg = (const float*)d_in[2];
    float* out = (float*)d_out;

    char* ws = (char*)d_ws;
    size_t off = 0;
    auto alloc = [&](size_t bytes) {
        void* p = ws + off;
        off += (bytes + 255) & ~(size_t)255;
        return p;
    };
    float* enorm  = (float*)alloc((size_t)NE * KD * 4);
    float* znorm  = (float*)alloc((size_t)T_TOK * KD * 4);
    short* Es     = (short*)alloc((size_t)NE * KE * 2);
    short* Zs     = (short*)alloc((size_t)T_TOK * KE * 2);
    float* e2k    = (float*)alloc(NE * 4);
    float* e2s    = (float*)alloc(NE * 4);
    float* z2k    = (float*)alloc(T_TOK * 4);
    float* z2s    = (float*)alloc(T_TOK * 4);
    u64*   packed = (u64*)alloc(T_TOK * 8);
    int*   ncand  = (int*)alloc(T_TOK * 4);
    float* candD  = (float*)alloc((size_t)T_TOK * CAP * 4);
    int*   candN  = (int*)alloc((size_t)T_TOK * CAP * 4);
    float* avg_num= (float*)alloc(NE * 4);
    float* scal   = (float*)alloc(8 * 4);
    float* Gbuf   = (float*)alloc(81920 * 4);
    float* SV     = (float*)alloc(1024 * 4);
    float* momv   = (float*)alloc(8 * 4);
    float* SVeS   = (float*)alloc((size_t)NCB * 256 * 4);
    float* SVeV   = (float*)alloc((size_t)NCB * 256 * 4);
    float* SVzS   = (float*)alloc((size_t)NZB * 256 * 4);
    float* SVzV   = (float*)alloc((size_t)NZB * 256 * 4);
    float* mompart= (float*)alloc((size_t)(NCB + NZB) * 4 * 4);
    int*   done_ctr = (int*)alloc(256);

    megaprep_kernel<<<NCB + NZB + 8, 256, 0, stream>>>(
        wk, wg, z, enorm, e2k, e2s, Es, znorm, z2k, z2s, Zs,
        SVeS, SVeV, SVzS, SVzV, mompart, packed, avg_num, ncand, scal, Gbuf, done_ctr);

    gemm_gram_kernel<<<NGRAM + NGEMM, 256, 0, stream>>>(
        Zs, Es, z2s, e2s, packed,
        candD, candN, ncand, znorm, enorm, Gbuf,
        SVeS, SVeV, SVzS, SVzV, mompart, SV, momv);

    combine_final_kernel<<<256, 256, 0, stream>>>(
        packed, enorm, znorm, z2s, e2s,
        candD, candN, ncand, avg_num, scal, done_ctr, Gbuf, SV, momv, out);
}